// Round 15
// baseline (506.866 us; speedup 1.0000x reference)
//
#include <hip/hip_runtime.h>

typedef __bf16 bf16;
typedef __bf16 bf16x8 __attribute__((ext_vector_type(8)));
typedef float  f32x4  __attribute__((ext_vector_type(4)));
typedef unsigned int u32x4 __attribute__((ext_vector_type(4)));

#define NB 2
#define SS 512
#define HH 2048
#define SUx 1024
#define TT 1536
#define INTERx 5632

// ---------------- async global -> LDS, 16B per lane ----------------
__device__ __forceinline__ void gload16(const void* g, void* l)
{
    __builtin_amdgcn_global_load_lds(
        (const __attribute__((address_space(1))) void*)g,
        (__attribute__((address_space(3))) void*)l, 16, 0, 0);
}

// ---------------- fused cast: all fp32->bf16 segments in ONE dispatch ----------------
struct CastArgs {
    const float* src[10];
    bf16*        dst[10];
    int          blk0[11];   // prefix block starts; blk0[10] = total blocks
};

__global__ __launch_bounds__(256)
void cast_all_k(CastArgs a)
{
    int b = blockIdx.x;
    int s = 0;
    #pragma unroll
    for (int i = 1; i < 10; ++i) if (b >= a.blk0[i]) s = i;
    long idx = ((long)(b - a.blk0[s]) * 256 + threadIdx.x) * 8;
    const float* in = a.src[s];
    bf16* out = a.dst[s];
    f32x4 va = *(const f32x4*)(in + idx);
    f32x4 vb = *(const f32x4*)(in + idx + 4);
    bf16x8 o;
    o[0]=(bf16)va[0]; o[1]=(bf16)va[1]; o[2]=(bf16)va[2]; o[3]=(bf16)va[3];
    o[4]=(bf16)vb[0]; o[5]=(bf16)vb[1]; o[6]=(bf16)vb[2]; o[7]=(bf16)vb[3];
    *(bf16x8*)(out + idx) = o;
}

// ------------- transpose [R][C] -> [C][R] (bf16 out), 64x64 tiles -------------
template <typename TIN>
__global__ __launch_bounds__(256)
void transpose_k(const TIN* __restrict__ in, bf16* __restrict__ out,
                 int inRS, int outRS, int nz2,
                 long inZ1, long inZ2, long outZ1, long outZ2)
{
    __shared__ bf16 tile[64][65];
    int z1 = blockIdx.z / nz2, z2 = blockIdx.z % nz2;
    const TIN* ip = in + (long)z1*inZ1 + (long)z2*inZ2
                  + (long)blockIdx.x*64*inRS + (long)blockIdx.y*64;
    bf16* op = out + (long)z1*outZ1 + (long)z2*outZ2
             + (long)blockIdx.y*64*outRS + (long)blockIdx.x*64;
    int tc = threadIdx.x & 63, tr = threadIdx.x >> 6;
    #pragma unroll
    for (int rr = 0; rr < 64; rr += 4)
        tile[rr+tr][tc] = (bf16)(float)ip[(long)(rr+tr)*inRS + tc];
    __syncthreads();
    #pragma unroll
    for (int cc = 0; cc < 64; cc += 4)
        op[(long)(cc+tr)*outRS + tc] = tile[tc][cc+tr];
}

// ---------------- RMSNorm over H=2048, one block per row ----------------
__global__ __launch_bounds__(256)
void rmsnorm_k(const float* __restrict__ x, const float* __restrict__ w,
               bf16* __restrict__ yb, float* __restrict__ yf)
{
    long row = blockIdx.x;
    const float* xp = x + row * HH;
    int t = threadIdx.x;
    f32x4 v0 = *(const f32x4*)(xp + t*8);
    f32x4 v1 = *(const f32x4*)(xp + t*8 + 4);
    float ss = 0.f;
    #pragma unroll
    for (int j = 0; j < 4; ++j) ss += v0[j]*v0[j] + v1[j]*v1[j];
    #pragma unroll
    for (int off = 32; off > 0; off >>= 1) ss += __shfl_xor(ss, off);
    __shared__ float red[4];
    if ((t & 63) == 0) red[t >> 6] = ss;
    __syncthreads();
    float tot = red[0] + red[1] + red[2] + red[3];
    float inv = rsqrtf(tot * (1.0f/(float)HH) + 1e-6f);
    f32x4 w0 = *(const f32x4*)(w + t*8);
    f32x4 w1 = *(const f32x4*)(w + t*8 + 4);
    f32x4 y0, y1; bf16x8 ob;
    #pragma unroll
    for (int j = 0; j < 4; ++j) {
        y0[j] = v0[j] * inv * w0[j];
        y1[j] = v1[j] * inv * w1[j];
        ob[j]   = (bf16)y0[j];
        ob[4+j] = (bf16)y1[j];
    }
    *(bf16x8*)(yb + row*HH + t*8) = ob;
    if (yf) {
        *(f32x4*)(yf + row*HH + t*8)     = y0;
        *(f32x4*)(yf + row*HH + t*8 + 4) = y1;
    }
}

// ---------------- GEMM body: 128x128 tile, 8 waves (2x4), 64x32 per wave ----------------
// r9-proven structure. BK template: 64 -> 64KB LDS (2 blocks/CU), 32 -> 32KB
// LDS (4 blocks/CU, thread-capped; for big-grid dispatches). Double-buffered
// global_load_lds, counted vmcnt (BK=64: 4 steady; BK=32: 2 steady; 0 last),
// raw s_barrier. Both-sides XOR swizzle (BK=64: ^(r&7) over 8 slots;
// BK=32: ^((r&3)^((r>>2)&3)) over 4 slots -> 2-way banks, free).
// GU=1: interleaved Wg/Wu rows + silu(g)*u epilogue via shfl_xor(1).
template <int GU, int BK>
__device__ __forceinline__
void gemm_body(const bf16* __restrict__ A, const bf16* __restrict__ Bw,
               int Nsplit, int K,
               long sA, long sB,
               bf16* __restrict__ Cb, bf16* __restrict__ Cb2, long sCb,
               float* __restrict__ C32, long sC32,
               const float* __restrict__ res, long sRes,
               const float* __restrict__ bias,
               float scale, int doSilu,
               int lin, int gx, int nwg,
               bf16* Asmem, bf16* Bsmem)
{
    constexpr int TILE = 128 * BK;          // elements per buffer
    constexpr int NOPS = (BK == 64) ? 2 : 1; // stage instrs per matrix per thread
    int z = blockIdx.z;
    const bf16* Ap = A + (long)z * sA;

    // XCD-aware bijective swizzle over the linearized grid
    int qq = nwg >> 3, r8 = nwg & 7;
    int xcd = lin & 7, off = lin >> 3;
    int wg = (xcd < r8 ? xcd * (qq + 1) : r8 * (qq + 1) + (xcd - r8) * qq) + off;
    int n0 = (wg % gx) * 128, m0 = (wg / gx) * 128;

    int t = threadIdx.x, lane = t & 63, w = t >> 6;
    int wr = w >> 2, wc = w & 3;            // 2x4 wave grid, 64x32 per wave
    int lc = lane & 15, lg = lane >> 4;

    const bf16* gA[NOPS]; const bf16* gB[NOPS];
    int ldsO[NOPS];
    #pragma unroll
    for (int i = 0; i < NOPS; ++i) {
        int r, s;
        if (BK == 64) {
            r = i*64 + (t >> 3);
            s = (t & 7) ^ (r & 7);
        } else {
            r = t >> 2;
            s = (t & 3) ^ ((r & 3) ^ ((r >> 2) & 3));
        }
        gA[i] = Ap + (long)(m0 + r) * K + s*8;
        if (GU) {
            long grow = (long)(n0 >> 1) + (r >> 1);
            gB[i] = Bw + ((r & 1) ? (long)INTERx * K : 0) + grow * K + s*8;
        } else {
            const bf16* Bp = Bw + (long)z * sB;
            gB[i] = Bp + (long)(n0 + r) * K + s*8;
        }
        ldsO[i] = i * 4096 + t * 8;          // elements (16B per thread per op)
    }

    f32x4 zero = {0.f, 0.f, 0.f, 0.f};
    f32x4 acc[4][2];
    #pragma unroll
    for (int i = 0; i < 4; ++i)
        #pragma unroll
        for (int j = 0; j < 2; ++j) acc[i][j] = zero;

    auto stage = [&](int buf, int ti) {
        long ko = (long)ti * BK;
        #pragma unroll
        for (int i = 0; i < NOPS; ++i) {
            gload16(gA[i] + ko, Asmem + buf*TILE + ldsO[i]);
            gload16(gB[i] + ko, Bsmem + buf*TILE + ldsO[i]);
        }
    };

    int NKI = K / BK;
    stage(0, 0);
    if (NKI > 1) stage(1, 1);

    for (int ks = 0; ks < NKI; ++ks) {
        int cur = ks & 1;
        const bf16* Asc = Asmem + cur * TILE;
        const bf16* Bsc = Bsmem + cur * TILE;

        if (ks == NKI - 1)      asm volatile("s_waitcnt vmcnt(0)" ::: "memory");
        else if (BK == 64)      asm volatile("s_waitcnt vmcnt(4)" ::: "memory");
        else                    asm volatile("s_waitcnt vmcnt(2)" ::: "memory");
        __builtin_amdgcn_s_barrier();
        __builtin_amdgcn_sched_barrier(0);

        #pragma unroll
        for (int kk = 0; kk < BK/32; ++kk) {
            bf16x8 af[4], bfv[2];
            #pragma unroll
            for (int i = 0; i < 4; ++i) {
                int rA = wr*64 + i*16 + lc;
                int sl = (BK == 64) ? ((kk*4 + lg) ^ (rA & 7))
                                    : (lg ^ ((rA & 3) ^ ((rA >> 2) & 3)));
                af[i]  = *(const bf16x8*)(Asc + rA*BK + sl*8);
            }
            #pragma unroll
            for (int j = 0; j < 2; ++j) {
                int rB = wc*32 + j*16 + lc;
                int sl = (BK == 64) ? ((kk*4 + lg) ^ (rB & 7))
                                    : (lg ^ ((rB & 3) ^ ((rB >> 2) & 3)));
                bfv[j] = *(const bf16x8*)(Bsc + rB*BK + sl*8);
            }
            __builtin_amdgcn_s_setprio(1);
            #pragma unroll
            for (int i = 0; i < 4; ++i)
                #pragma unroll
                for (int j = 0; j < 2; ++j)
                    acc[i][j] = __builtin_amdgcn_mfma_f32_16x16x32_bf16(af[i], bfv[j], acc[i][j], 0, 0, 0);
            __builtin_amdgcn_s_setprio(0);
        }

        __builtin_amdgcn_s_barrier();
        if (ks + 2 < NKI) stage(cur, ks + 2);
    }

    if (GU) {
        #pragma unroll
        for (int i = 0; i < 4; ++i) {
            #pragma unroll
            for (int j = 0; j < 2; ++j) {
                int tc2 = wc*32 + j*16 + lc;
                int colp = (n0 >> 1) + (tc2 >> 1);
                #pragma unroll
                for (int r = 0; r < 4; ++r) {
                    int row = m0 + wr*64 + i*16 + lg*4 + r;
                    float v = acc[i][j][r];
                    float pv = __shfl_xor(v, 1);
                    float g  = (lc & 1) ? pv : v;
                    float uu = (lc & 1) ? v  : pv;
                    float prod = (g / (1.f + __expf(-g))) * uu;
                    if (!(lc & 1))
                        Cb[(long)row * Nsplit + colp] = (bf16)prod;
                }
            }
        }
    } else {
        #pragma unroll
        for (int i = 0; i < 4; ++i) {
            #pragma unroll
            for (int j = 0; j < 2; ++j) {
                int col = n0 + wc*32 + j*16 + lc;
                bf16* dst = Cb; int c2 = col;
                if (Cb2 && col >= Nsplit) { dst = Cb2; c2 = col - Nsplit; }
                int firstHalf = (col < Nsplit);
                #pragma unroll
                for (int r = 0; r < 4; ++r) {
                    int row = m0 + wr*64 + i*16 + lg*4 + r;
                    float v = acc[i][j][r] * scale;
                    if (bias)   v += bias[row];
                    if (doSilu && firstHalf) v = v / (1.f + __expf(-v));
                    long off = (long)row * Nsplit + c2;
                    if (res)  v += res[(long)z * sRes + off];
                    if (C32)  C32[(long)z * sC32 + off] = v;
                    if (dst)  dst[(long)z * sCb + off] = (bf16)v;
                }
            }
        }
    }
}

// standard wrapper: 2D/3D grid
template <int GU, int BK>
__global__ __launch_bounds__(512)
void gemm_k(const bf16* __restrict__ A, const bf16* __restrict__ Bw,
            int Nsplit, int K,
            long sA, long sB,
            bf16* __restrict__ Cb, bf16* __restrict__ Cb2, long sCb,
            float* __restrict__ C32, long sC32,
            const float* __restrict__ res, long sRes,
            const float* __restrict__ bias,
            float scale, int doSilu)
{
    __shared__ alignas(16) bf16 As[2][128 * BK];
    __shared__ alignas(16) bf16 Bs[2][128 * BK];
    int gx = gridDim.x;
    int nwg = gx * gridDim.y;
    int lin = blockIdx.y * gx + blockIdx.x;
    gemm_body<GU, BK>(A, Bw, Nsplit, K, sA, sB, Cb, Cb2, sCb, C32, sC32,
                      res, sRes, bias, scale, doSilu, lin, gx, nwg,
                      &As[0][0], &Bs[0][0]);
}

// merged Q + K|V projections (BK=32, 32KB LDS -> 4 blocks/CU):
// blocks 0..255 -> Q (16x16), 256..1023 -> K|V (32x24)
__global__ __launch_bounds__(512)
void qkv_k(const bf16* __restrict__ x1b, const bf16* __restrict__ wq,
           bf16* __restrict__ qb,
           const bf16* __restrict__ resb, const bf16* __restrict__ wk,
           bf16* __restrict__ kb, bf16* __restrict__ vb)
{
    __shared__ alignas(16) bf16 As[2][128 * 32];
    __shared__ alignas(16) bf16 Bs[2][128 * 32];
    int lin = blockIdx.x;
    if (lin < 256) {
        gemm_body<0, 32>(x1b, wq, HH, HH, 0, 0, qb, nullptr, 0, nullptr, 0,
                         nullptr, 0, nullptr, 0.125f, 0, lin, 16, 256,
                         &As[0][0], &Bs[0][0]);
    } else {
        gemm_body<0, 32>(resb, wk, HH, HH, 0, 0, kb, vb, 0, nullptr, 0,
                         nullptr, 0, nullptr, 1.0f, 0, lin - 256, 32, 768,
                         &As[0][0], &Bs[0][0]);
    }
}

// ---------------- flash attention: 8 waves/block, LDS-shared K/V (r7) ----------------
__global__ __launch_bounds__(512)
void attn_k(const bf16* __restrict__ q, const bf16* __restrict__ k,
            const bf16* __restrict__ vt, bf16* __restrict__ o)
{
    int qc = blockIdx.x, h = blockIdx.y, b = blockIdx.z;
    int t = threadIdx.x, lane = t & 63, w = t >> 6;
    int lc = lane & 15, lg = lane >> 4;
    const bf16* qp = q  + ((long)(b*SUx + qc*256 + w*32)) * HH + h*64;
    const bf16* kp = k  + ((long)b*TT) * HH + h*64;
    const bf16* vp = vt + ((long)(b*32 + h)) * 64 * TT;

    __shared__ alignas(16) bf16 Ks[2][64*64];
    __shared__ alignas(16) bf16 Vs[2][64*64];
    __shared__ alignas(16) bf16 Ps[8][2][16*72];

    bf16x8 qf[2][2];
    #pragma unroll
    for (int s = 0; s < 2; ++s)
        #pragma unroll
        for (int kk = 0; kk < 2; ++kk)
            qf[s][kk] = *(const bf16x8*)(qp + (long)(s*16 + lc)*HH + kk*32 + lg*8);

    int lr = lane >> 3, ls = lane & 7;
    int srow = w*8 + lr;
    int sslot = ls ^ lr;
    const bf16* gK = kp + (long)srow * HH + sslot*8;
    const bf16* gV = vp + (long)srow * TT + sslot*8;
    int ldsO = w * 512;

    f32x4 zero = {0.f, 0.f, 0.f, 0.f};
    f32x4 oacc[2][4];
    float lsum[2][4];
    #pragma unroll
    for (int qs = 0; qs < 2; ++qs) {
        #pragma unroll
        for (int r = 0; r < 4; ++r) lsum[qs][r] = 0.f;
        #pragma unroll
        for (int dt = 0; dt < 4; ++dt) oacc[qs][dt] = zero;
    }

    const int NS = TT / 64;
    gload16(gK,            &Ks[0][0] + ldsO);
    gload16(gV,            &Vs[0][0] + ldsO);
    gload16(gK + 64L*HH,   &Ks[1][0] + ldsO);
    gload16(gV + 64,       &Vs[1][0] + ldsO);

    for (int st = 0; st < NS; ++st) {
        int cur = st & 1;
        const bf16* Kc = &Ks[cur][0];
        const bf16* Vc = &Vs[cur][0];

        if (st == NS - 1) asm volatile("s_waitcnt vmcnt(0)" ::: "memory");
        else              asm volatile("s_waitcnt vmcnt(2)" ::: "memory");
        __builtin_amdgcn_s_barrier();
        __builtin_amdgcn_sched_barrier(0);

        bf16x8 kf[4][2];
        #pragma unroll
        for (int s2 = 0; s2 < 4; ++s2) {
            int row = s2*16 + lc;
            #pragma unroll
            for (int kk = 0; kk < 2; ++kk)
                kf[s2][kk] = *(const bf16x8*)(Kc + row*64 + (((kk*4 + lg) ^ (row & 7)) * 8));
        }
        f32x4 sv[2][4];
        __builtin_amdgcn_s_setprio(1);
        #pragma unroll
        for (int qs = 0; qs < 2; ++qs)
            #pragma unroll
            for (int s2 = 0; s2 < 4; ++s2) {
                f32x4 a0 = __builtin_amdgcn_mfma_f32_16x16x32_bf16(qf[qs][0], kf[s2][0], zero, 0, 0, 0);
                sv[qs][s2] = __builtin_amdgcn_mfma_f32_16x16x32_bf16(qf[qs][1], kf[s2][1], a0, 0, 0, 0);
            }
        __builtin_amdgcn_s_setprio(0);

        bf16* Pw = &Ps[w][0][0];
        #pragma unroll
        for (int qs = 0; qs < 2; ++qs)
            #pragma unroll
            for (int r = 0; r < 4; ++r) {
                int prow = lg*4 + r;
                #pragma unroll
                for (int s2 = 0; s2 < 4; ++s2) {
                    float pp = __expf(sv[qs][s2][r]);
                    lsum[qs][r] += pp;
                    Pw[qs*(16*72) + prow*72 + s2*16 + lc] = (bf16)pp;
                }
            }
        asm volatile("s_waitcnt lgkmcnt(0)" ::: "memory");
        __builtin_amdgcn_sched_barrier(0);

        bf16x8 pf[2][2];
        #pragma unroll
        for (int qs = 0; qs < 2; ++qs)
            #pragma unroll
            for (int ks = 0; ks < 2; ++ks)
                pf[qs][ks] = *(const bf16x8*)(Pw + qs*(16*72) + lc*72 + (ks*4 + lg)*8);
        bf16x8 vf[4][2];
        #pragma unroll
        for (int dt = 0; dt < 4; ++dt) {
            int row = dt*16 + lc;
            #pragma unroll
            for (int ks = 0; ks < 2; ++ks)
                vf[dt][ks] = *(const bf16x8*)(Vc + row*64 + (((ks*4 + lg) ^ (row & 7)) * 8));
        }
        __builtin_amdgcn_s_setprio(1);
        #pragma unroll
        for (int qs = 0; qs < 2; ++qs)
            #pragma unroll
            for (int dt = 0; dt < 4; ++dt) {
                oacc[qs][dt] = __builtin_amdgcn_mfma_f32_16x16x32_bf16(pf[qs][0], vf[dt][0], oacc[qs][dt], 0, 0, 0);
                oacc[qs][dt] = __builtin_amdgcn_mfma_f32_16x16x32_bf16(pf[qs][1], vf[dt][1], oacc[qs][dt], 0, 0, 0);
            }
        __builtin_amdgcn_s_setprio(0);

        __builtin_amdgcn_s_barrier();
        if (st + 2 < NS) {
            long t2 = (long)(st + 2) * 64;
            gload16(gK + t2*HH, (bf16*)Kc + ldsO);
            gload16(gV + t2,    (bf16*)Vc + ldsO);
        }
    }

    #pragma unroll
    for (int qs = 0; qs < 2; ++qs)
        #pragma unroll
        for (int r = 0; r < 4; ++r) {
            float l = lsum[qs][r];
            l += __shfl_xor(l, 1);
            l += __shfl_xor(l, 2);
            l += __shfl_xor(l, 4);
            l += __shfl_xor(l, 8);
            float inv = 1.0f / l;
            long row = (long)b*SUx + qc*256 + w*32 + qs*16 + lg*4 + r;
            #pragma unroll
            for (int dt = 0; dt < 4; ++dt)
                o[row*HH + h*64 + dt*16 + lc] = (bf16)(oacc[qs][dt][r] * inv);
        }
}

// =============================== launcher ===============================
extern "C" void kernel_launch(void* const* d_in, const int* in_sizes, int n_in,
                              void* d_out, int out_size, void* d_ws, size_t ws_size,
                              hipStream_t stream)
{
    const float* hs  = (const float*)d_in[0];
    const float* Wup = (const float*)d_in[1];
    const float* bup = (const float*)d_in[2];
    const float* anw = (const float*)d_in[3];
    const float* Wq  = (const float*)d_in[4];
    const float* Wk  = (const float*)d_in[5];
    const float* Wv  = (const float*)d_in[6];
    const float* Wo  = (const float*)d_in[7];
    const float* mnw = (const float*)d_in[8];
    const float* Wg  = (const float*)d_in[9];
    const float* Wu  = (const float*)d_in[10];
    const float* Wd  = (const float*)d_in[11];
    float* outp = (float*)d_out;

    char* p = (char*)d_ws;
    auto take = [&](size_t bytes) -> void* {
        void* r = (void*)p;
        p += (bytes + 255) & ~(size_t)255;
        return r;
    };

    bf16* wq  = (bf16*)take((size_t)HH*HH*2);
    bf16* wk  = (bf16*)take(2 * (size_t)HH*HH*2);      // wv contiguous after wk
    bf16* wv  = wk + (size_t)HH*HH;
    bf16* wo  = (bf16*)take((size_t)HH*HH*2);
    bf16* wgu = (bf16*)take(2 * (size_t)INTERx*HH*2);  // [Wg ; Wu] contiguous
    bf16* wd  = (bf16*)take((size_t)INTERx*HH*2);
    bf16* wup = (bf16*)take((size_t)SUx*SS*2);
    bf16* ht  = (bf16*)take((size_t)NB*HH*SS*2);
    bf16* resb= (bf16*)take((size_t)NB*TT*HH*2);
    float* x1f= (float*)take((size_t)NB*SUx*HH*4);
    bf16* x1b = (bf16*)take((size_t)NB*SUx*HH*2);
    float* upf= (float*)take((size_t)NB*SUx*HH*4);   // later reused as x_attn

    size_t attn_bytes = (size_t)NB*SUx*HH*2 + 3*(size_t)NB*TT*HH*2 + (size_t)NB*SUx*HH*2;
    size_t mlp_bytes  = (size_t)NB*SUx*HH*4 + (size_t)NB*SUx*HH*2 + (size_t)NB*SUx*INTERx*2;
    char* un = (char*)take(attn_bytes > mlp_bytes ? attn_bytes : mlp_bytes);
    bf16* qb  = (bf16*)un;
    bf16* kb  = qb  + (size_t)NB*SUx*HH;
    bf16* vb  = kb  + (size_t)NB*TT*HH;
    bf16* vtb = vb  + (size_t)NB*TT*HH;
    bf16* ob  = vtb + (size_t)NB*TT*HH;
    float* x2f= (float*)un;
    bf16* x2b = (bf16*)(un + (size_t)NB*SUx*HH*4);
    bf16* gb  = x2b + (size_t)NB*SUx*HH;

    // ---- 1. single fused cast dispatch ----
    CastArgs ca;
    int blk = 0;
    auto seg = [&](int i, const float* s, bf16* d, long nelem) {
        ca.src[i] = s; ca.dst[i] = d; ca.blk0[i] = blk;
        blk += (int)(nelem / 2048);
    };
    seg(0, Wq,  wq,  (long)HH*HH);
    seg(1, Wk,  wk,  (long)HH*HH);
    seg(2, Wv,  wv,  (long)HH*HH);
    seg(3, Wo,  wo,  (long)HH*HH);
    seg(4, Wg,  wgu, (long)INTERx*HH);
    seg(5, Wu,  wgu + (size_t)INTERx*HH, (long)INTERx*HH);
    seg(6, Wd,  wd,  (long)INTERx*HH);
    seg(7, Wup, wup, (long)SUx*SS);
    seg(8, hs,                 resb,                   (long)SS*HH);
    seg(9, hs + (size_t)SS*HH, resb + (size_t)TT*HH,   (long)SS*HH);
    ca.blk0[10] = blk;
    cast_all_k<<<dim3(blk), 256, 0, stream>>>(ca);

    // ---- 2. h^T (bf16): [b][s][d] -> [b][d][s] ----
    transpose_k<float><<<dim3(SS/64, HH/64, NB), 256, 0, stream>>>(
        hs, ht, HH, SS, 1, (long)SS*HH, 0, (long)HH*SS, 0);

    // ---- 3. upsample: up[b,t,d] = sum_s Wup[t,s] h[b,s,d] + bup[t] ----
    gemm_k<0, 64><<<dim3(HH/128, SUx/128, NB), 512, 0, stream>>>(
        wup, ht, HH, SS, 0, (long)HH*SS,
        resb + (size_t)SS*HH, nullptr, (long)TT*HH,
        upf, (long)SUx*HH,
        nullptr, 0, bup, 1.0f, 0);

    // ---- 4. x1 = rmsnorm(up) ----
    rmsnorm_k<<<dim3(NB*SUx), 256, 0, stream>>>(upf, anw, x1b, x1f);

    // ---- 5. merged Q + K|V projections (1024 blocks, BK=32 -> 4 blocks/CU) ----
    qkv_k<<<dim3(1024), 512, 0, stream>>>(x1b, wq, qb, resb, wk, kb, vb);

    // ---- 6. V^T per head ----
    transpose_k<bf16><<<dim3(TT/64, 1, NB*32), 256, 0, stream>>>(
        vb, vtb, HH, TT, 32, (long)TT*HH, 64, (long)32*64*TT, (long)64*TT);

    // ---- 7. attention ----
    attn_k<<<dim3(SUx/256, 32, NB), 512, 0, stream>>>(qb, kb, vtb, ob);

    // ---- 8. x_attn = o @ Wo^T + x1 ----
    gemm_k<0, 64><<<dim3(HH/128, (NB*SUx)/128, 1), 512, 0, stream>>>(
        ob, wo, HH, HH, 0, 0, nullptr, nullptr, 0, upf, 0, x1f, 0, nullptr, 1.0f, 0);

    // ---- 9. x2 = rmsnorm(x_attn) ----
    rmsnorm_k<<<dim3(NB*SUx), 256, 0, stream>>>(upf, mnw, x2b, x2f);

    // ---- 10. gated MLP, fully fused (1408 blocks, BK=32 -> 4 blocks/CU) ----
    gemm_k<1, 32><<<dim3((2*INTERx)/128, (NB*SUx)/128, 1), 512, 0, stream>>>(
        x2b, wgu, INTERx, HH, 0, 0, gb, nullptr, 0, nullptr, 0, nullptr, 0, nullptr, 1.0f, 0);

    // ---- 11. out = gb @ Wd^T + x2 ----
    gemm_k<0, 64><<<dim3(HH/128, (NB*SUx)/128, 1), 512, 0, stream>>>(
        gb, wd, HH, INTERx, 0, 0, nullptr, nullptr, 0, outp, 0, x2f, 0, nullptr, 1.0f, 0);

    (void)in_sizes; (void)n_in; (void)out_size; (void)ws_size;
}

// Round 16
// 465.162 us; speedup vs baseline: 1.0897x; 1.0897x over previous
//
#include <hip/hip_runtime.h>

typedef __bf16 bf16;
typedef __bf16 bf16x8 __attribute__((ext_vector_type(8)));
typedef float  f32x4  __attribute__((ext_vector_type(4)));
typedef unsigned int u32x4 __attribute__((ext_vector_type(4)));

#define NB 2
#define SS 512
#define HH 2048
#define SUx 1024
#define TT 1536
#define INTERx 5632

// ---------------- async global -> LDS, 16B per lane ----------------
__device__ __forceinline__ void gload16(const void* g, void* l)
{
    __builtin_amdgcn_global_load_lds(
        (const __attribute__((address_space(1))) void*)g,
        (__attribute__((address_space(3))) void*)l, 16, 0, 0);
}

// ---------------- fused cast: all fp32->bf16 segments in ONE dispatch ----------------
struct CastArgs {
    const float* src[10];
    bf16*        dst[10];
    int          blk0[11];   // prefix block starts; blk0[10] = total blocks
};

__global__ __launch_bounds__(256)
void cast_all_k(CastArgs a)
{
    int b = blockIdx.x;
    int s = 0;
    #pragma unroll
    for (int i = 1; i < 10; ++i) if (b >= a.blk0[i]) s = i;
    long idx = ((long)(b - a.blk0[s]) * 256 + threadIdx.x) * 8;
    const float* in = a.src[s];
    bf16* out = a.dst[s];
    f32x4 va = *(const f32x4*)(in + idx);
    f32x4 vb = *(const f32x4*)(in + idx + 4);
    bf16x8 o;
    o[0]=(bf16)va[0]; o[1]=(bf16)va[1]; o[2]=(bf16)va[2]; o[3]=(bf16)va[3];
    o[4]=(bf16)vb[0]; o[5]=(bf16)vb[1]; o[6]=(bf16)vb[2]; o[7]=(bf16)vb[3];
    *(bf16x8*)(out + idx) = o;
}

// ------------- transpose [R][C] -> [C][R] (bf16 out), 64x64 tiles -------------
template <typename TIN>
__global__ __launch_bounds__(256)
void transpose_k(const TIN* __restrict__ in, bf16* __restrict__ out,
                 int inRS, int outRS, int nz2,
                 long inZ1, long inZ2, long outZ1, long outZ2)
{
    __shared__ bf16 tile[64][65];
    int z1 = blockIdx.z / nz2, z2 = blockIdx.z % nz2;
    const TIN* ip = in + (long)z1*inZ1 + (long)z2*inZ2
                  + (long)blockIdx.x*64*inRS + (long)blockIdx.y*64;
    bf16* op = out + (long)z1*outZ1 + (long)z2*outZ2
             + (long)blockIdx.y*64*outRS + (long)blockIdx.x*64;
    int tc = threadIdx.x & 63, tr = threadIdx.x >> 6;
    #pragma unroll
    for (int rr = 0; rr < 64; rr += 4)
        tile[rr+tr][tc] = (bf16)(float)ip[(long)(rr+tr)*inRS + tc];
    __syncthreads();
    #pragma unroll
    for (int cc = 0; cc < 64; cc += 4)
        op[(long)(cc+tr)*outRS + tc] = tile[tc][cc+tr];
}

// ---------------- RMSNorm over H=2048, one block per row ----------------
__global__ __launch_bounds__(256)
void rmsnorm_k(const float* __restrict__ x, const float* __restrict__ w,
               bf16* __restrict__ yb, float* __restrict__ yf)
{
    long row = blockIdx.x;
    const float* xp = x + row * HH;
    int t = threadIdx.x;
    f32x4 v0 = *(const f32x4*)(xp + t*8);
    f32x4 v1 = *(const f32x4*)(xp + t*8 + 4);
    float ss = 0.f;
    #pragma unroll
    for (int j = 0; j < 4; ++j) ss += v0[j]*v0[j] + v1[j]*v1[j];
    #pragma unroll
    for (int off = 32; off > 0; off >>= 1) ss += __shfl_xor(ss, off);
    __shared__ float red[4];
    if ((t & 63) == 0) red[t >> 6] = ss;
    __syncthreads();
    float tot = red[0] + red[1] + red[2] + red[3];
    float inv = rsqrtf(tot * (1.0f/(float)HH) + 1e-6f);
    f32x4 w0 = *(const f32x4*)(w + t*8);
    f32x4 w1 = *(const f32x4*)(w + t*8 + 4);
    f32x4 y0, y1; bf16x8 ob;
    #pragma unroll
    for (int j = 0; j < 4; ++j) {
        y0[j] = v0[j] * inv * w0[j];
        y1[j] = v1[j] * inv * w1[j];
        ob[j]   = (bf16)y0[j];
        ob[4+j] = (bf16)y1[j];
    }
    *(bf16x8*)(yb + row*HH + t*8) = ob;
    if (yf) {
        *(f32x4*)(yf + row*HH + t*8)     = y0;
        *(f32x4*)(yf + row*HH + t*8 + 4) = y1;
    }
}

// ---------------- GEMM body: 128x128 tile, BK=64, 8 waves (2x4), 64x32/wave ----------------
// r9-proven structure: double-buffered global_load_lds, counted vmcnt(4)
// steady / (0) last, raw s_barrier, both-sides XOR swizzle (8-slot, 128B rows,
// conflict-free measured), XCD-bijective block swizzle.
// GU=1 (MLP): interleaved Wg/Wu rows + silu(g)*u epilogue via shfl_xor(1),
//   and L2 super-tile decode: within each XCD, 8-M-row strips swept panel-by-
//   panel so the concurrent working set is ~8 A-panels + 8 B-panels (fits L2);
//   each B panel fetched ~2x per XCD instead of ~8x (FETCH was 368MB = 8x B).
template <int GU>
__device__ __forceinline__
void gemm_body(const bf16* __restrict__ A, const bf16* __restrict__ Bw,
               int Nsplit, int K,
               long sA, long sB,
               bf16* __restrict__ Cb, bf16* __restrict__ Cb2, long sCb,
               float* __restrict__ C32, long sC32,
               const float* __restrict__ res, long sRes,
               const float* __restrict__ bias,
               float scale, int doSilu,
               int lin, int gx, int nwg,
               bf16* Asmem, bf16* Bsmem)
{
    int z = blockIdx.z;
    const bf16* Ap = A + (long)z * sA;

    int n0, m0;
    if (GU) {
        // MLP grid: gx = 88 panels (x), gy = 16 m-blocks. nwg = 1408 = 8*176.
        // xcd c owns panels [11c, 11c+11). Within XCD: strip a (8 m-rows),
        // panel sweep inside strip, m fastest inside panel.
        int c = lin & 7, off = lin >> 3;          // off in [0,176)
        int gx8 = gx >> 3;                        // 11 panels per XCD
        int perStrip = gx8 * 8;                   // 88 blocks per strip
        int a = off / perStrip;                   // strip 0..1
        int r = off - a * perStrip;
        int m = a * 8 + (r & 7);
        int nIdx = c * gx8 + (r >> 3);
        n0 = nIdx * 128; m0 = m * 128;
    } else {
        int qq = nwg >> 3, r8 = nwg & 7;
        int xcd = lin & 7, off = lin >> 3;
        int wg = (xcd < r8 ? xcd * (qq + 1) : r8 * (qq + 1) + (xcd - r8) * qq) + off;
        n0 = (wg % gx) * 128; m0 = (wg / gx) * 128;
    }

    int t = threadIdx.x, lane = t & 63, w = t >> 6;
    int wr = w >> 2, wc = w & 3;            // 2x4 wave grid, 64x32 per wave
    int lc = lane & 15, lg = lane >> 4;

    // staging: code-instr i, wave w covers LDS rows (i*8+w)*8 .. +8.
    // lane l -> row += (l>>3), slot s' = l&7; source slot s = s' ^ (row&7).
    int lr = lane >> 3, ls = lane & 7;
    const bf16* gA[2]; const bf16* gB[2];
    int ldsOff[2];
    #pragma unroll
    for (int i = 0; i < 2; ++i) {
        int r = (i*8 + w)*8 + lr;
        gA[i] = Ap + (long)(m0 + r) * K + (ls ^ lr) * 8;
        if (GU) {
            long grow = (long)(n0 >> 1) + (r >> 1);
            gB[i] = Bw + ((r & 1) ? (long)INTERx * K : 0) + grow * K + (ls ^ lr) * 8;
        } else {
            const bf16* Bp = Bw + (long)z * sB;
            gB[i] = Bp + (long)(n0 + r) * K + (ls ^ lr) * 8;
        }
        ldsOff[i] = (i*8 + w) * 512;
    }

    f32x4 zero = {0.f, 0.f, 0.f, 0.f};
    f32x4 acc[4][2];
    #pragma unroll
    for (int i = 0; i < 4; ++i)
        #pragma unroll
        for (int j = 0; j < 2; ++j) acc[i][j] = zero;

    int NKI = K >> 6;
    #pragma unroll
    for (int i = 0; i < 2; ++i) {
        gload16(gA[i], Asmem + ldsOff[i]);
        gload16(gB[i], Bsmem + ldsOff[i]);
    }
    if (NKI > 1) {
        #pragma unroll
        for (int i = 0; i < 2; ++i) {
            gload16(gA[i] + 64, Asmem + 128*64 + ldsOff[i]);
            gload16(gB[i] + 64, Bsmem + 128*64 + ldsOff[i]);
        }
    }

    for (int ks = 0; ks < NKI; ++ks) {
        int cur = ks & 1;
        const bf16* Asc = Asmem + cur * (128*64);
        const bf16* Bsc = Bsmem + cur * (128*64);

        if (ks == NKI - 1) asm volatile("s_waitcnt vmcnt(0)" ::: "memory");
        else               asm volatile("s_waitcnt vmcnt(4)" ::: "memory");
        __builtin_amdgcn_s_barrier();
        __builtin_amdgcn_sched_barrier(0);

        #pragma unroll
        for (int kk = 0; kk < 2; ++kk) {
            bf16x8 af[4], bfv[2];
            #pragma unroll
            for (int i = 0; i < 4; ++i) {
                int rA = wr*64 + i*16 + lc;
                af[i]  = *(const bf16x8*)(Asc + rA*64 + (((kk*4 + lg) ^ (rA & 7)) * 8));
            }
            #pragma unroll
            for (int j = 0; j < 2; ++j) {
                int rB = wc*32 + j*16 + lc;
                bfv[j] = *(const bf16x8*)(Bsc + rB*64 + (((kk*4 + lg) ^ (rB & 7)) * 8));
            }
            __builtin_amdgcn_s_setprio(1);
            #pragma unroll
            for (int i = 0; i < 4; ++i)
                #pragma unroll
                for (int j = 0; j < 2; ++j)
                    acc[i][j] = __builtin_amdgcn_mfma_f32_16x16x32_bf16(af[i], bfv[j], acc[i][j], 0, 0, 0);
            __builtin_amdgcn_s_setprio(0);
        }

        __builtin_amdgcn_s_barrier();
        if (ks + 2 < NKI) {
            long ko = (long)(ks + 2) * 64;
            #pragma unroll
            for (int i = 0; i < 2; ++i) {
                gload16(gA[i] + ko, (bf16*)Asc + ldsOff[i]);
                gload16(gB[i] + ko, (bf16*)Bsc + ldsOff[i]);
            }
        }
    }

    if (GU) {
        #pragma unroll
        for (int i = 0; i < 4; ++i) {
            #pragma unroll
            for (int j = 0; j < 2; ++j) {
                int tc2 = wc*32 + j*16 + lc;
                int colp = (n0 >> 1) + (tc2 >> 1);
                #pragma unroll
                for (int r = 0; r < 4; ++r) {
                    int row = m0 + wr*64 + i*16 + lg*4 + r;
                    float v = acc[i][j][r];
                    float pv = __shfl_xor(v, 1);
                    float g  = (lc & 1) ? pv : v;
                    float uu = (lc & 1) ? v  : pv;
                    float prod = (g / (1.f + __expf(-g))) * uu;
                    if (!(lc & 1))
                        Cb[(long)row * Nsplit + colp] = (bf16)prod;
                }
            }
        }
    } else {
        #pragma unroll
        for (int i = 0; i < 4; ++i) {
            #pragma unroll
            for (int j = 0; j < 2; ++j) {
                int col = n0 + wc*32 + j*16 + lc;
                bf16* dst = Cb; int c2 = col;
                if (Cb2 && col >= Nsplit) { dst = Cb2; c2 = col - Nsplit; }
                int firstHalf = (col < Nsplit);
                #pragma unroll
                for (int r = 0; r < 4; ++r) {
                    int row = m0 + wr*64 + i*16 + lg*4 + r;
                    float v = acc[i][j][r] * scale;
                    if (bias)   v += bias[row];
                    if (doSilu && firstHalf) v = v / (1.f + __expf(-v));
                    long off = (long)row * Nsplit + c2;
                    if (res)  v += res[(long)z * sRes + off];
                    if (C32)  C32[(long)z * sC32 + off] = v;
                    if (dst)  dst[(long)z * sCb + off] = (bf16)v;
                }
            }
        }
    }
}

// standard wrapper: 2D/3D grid
template <int GU>
__global__ __launch_bounds__(512)
void gemm_k(const bf16* __restrict__ A, const bf16* __restrict__ Bw,
            int Nsplit, int K,
            long sA, long sB,
            bf16* __restrict__ Cb, bf16* __restrict__ Cb2, long sCb,
            float* __restrict__ C32, long sC32,
            const float* __restrict__ res, long sRes,
            const float* __restrict__ bias,
            float scale, int doSilu)
{
    __shared__ alignas(16) bf16 As[2][128 * 64];
    __shared__ alignas(16) bf16 Bs[2][128 * 64];
    int gx = gridDim.x;
    int nwg = gx * gridDim.y;
    int lin = blockIdx.y * gx + blockIdx.x;
    gemm_body<GU>(A, Bw, Nsplit, K, sA, sB, Cb, Cb2, sCb, C32, sC32,
                  res, sRes, bias, scale, doSilu, lin, gx, nwg,
                  &As[0][0], &Bs[0][0]);
}

// merged Q + K|V projections: blocks 0..255 -> Q (16x16), 256..1023 -> K|V (32x24)
__global__ __launch_bounds__(512)
void qkv_k(const bf16* __restrict__ x1b, const bf16* __restrict__ wq,
           bf16* __restrict__ qb,
           const bf16* __restrict__ resb, const bf16* __restrict__ wk,
           bf16* __restrict__ kb, bf16* __restrict__ vb)
{
    __shared__ alignas(16) bf16 As[2][128 * 64];
    __shared__ alignas(16) bf16 Bs[2][128 * 64];
    int lin = blockIdx.x;
    if (lin < 256) {
        gemm_body<0>(x1b, wq, HH, HH, 0, 0, qb, nullptr, 0, nullptr, 0,
                     nullptr, 0, nullptr, 0.125f, 0, lin, 16, 256,
                     &As[0][0], &Bs[0][0]);
    } else {
        gemm_body<0>(resb, wk, HH, HH, 0, 0, kb, vb, 0, nullptr, 0,
                     nullptr, 0, nullptr, 1.0f, 0, lin - 256, 32, 768,
                     &As[0][0], &Bs[0][0]);
    }
}

// ---------------- flash attention: 8 waves/block, LDS-shared K/V (r7) ----------------
__global__ __launch_bounds__(512)
void attn_k(const bf16* __restrict__ q, const bf16* __restrict__ k,
            const bf16* __restrict__ vt, bf16* __restrict__ o)
{
    int qc = blockIdx.x, h = blockIdx.y, b = blockIdx.z;
    int t = threadIdx.x, lane = t & 63, w = t >> 6;
    int lc = lane & 15, lg = lane >> 4;
    const bf16* qp = q  + ((long)(b*SUx + qc*256 + w*32)) * HH + h*64;
    const bf16* kp = k  + ((long)b*TT) * HH + h*64;
    const bf16* vp = vt + ((long)(b*32 + h)) * 64 * TT;

    __shared__ alignas(16) bf16 Ks[2][64*64];
    __shared__ alignas(16) bf16 Vs[2][64*64];
    __shared__ alignas(16) bf16 Ps[8][2][16*72];

    bf16x8 qf[2][2];
    #pragma unroll
    for (int s = 0; s < 2; ++s)
        #pragma unroll
        for (int kk = 0; kk < 2; ++kk)
            qf[s][kk] = *(const bf16x8*)(qp + (long)(s*16 + lc)*HH + kk*32 + lg*8);

    int lr = lane >> 3, ls = lane & 7;
    int srow = w*8 + lr;
    int sslot = ls ^ lr;
    const bf16* gK = kp + (long)srow * HH + sslot*8;
    const bf16* gV = vp + (long)srow * TT + sslot*8;
    int ldsO = w * 512;

    f32x4 zero = {0.f, 0.f, 0.f, 0.f};
    f32x4 oacc[2][4];
    float lsum[2][4];
    #pragma unroll
    for (int qs = 0; qs < 2; ++qs) {
        #pragma unroll
        for (int r = 0; r < 4; ++r) lsum[qs][r] = 0.f;
        #pragma unroll
        for (int dt = 0; dt < 4; ++dt) oacc[qs][dt] = zero;
    }

    const int NS = TT / 64;
    gload16(gK,            &Ks[0][0] + ldsO);
    gload16(gV,            &Vs[0][0] + ldsO);
    gload16(gK + 64L*HH,   &Ks[1][0] + ldsO);
    gload16(gV + 64,       &Vs[1][0] + ldsO);

    for (int st = 0; st < NS; ++st) {
        int cur = st & 1;
        const bf16* Kc = &Ks[cur][0];
        const bf16* Vc = &Vs[cur][0];

        if (st == NS - 1) asm volatile("s_waitcnt vmcnt(0)" ::: "memory");
        else              asm volatile("s_waitcnt vmcnt(2)" ::: "memory");
        __builtin_amdgcn_s_barrier();
        __builtin_amdgcn_sched_barrier(0);

        bf16x8 kf[4][2];
        #pragma unroll
        for (int s2 = 0; s2 < 4; ++s2) {
            int row = s2*16 + lc;
            #pragma unroll
            for (int kk = 0; kk < 2; ++kk)
                kf[s2][kk] = *(const bf16x8*)(Kc + row*64 + (((kk*4 + lg) ^ (row & 7)) * 8));
        }
        f32x4 sv[2][4];
        __builtin_amdgcn_s_setprio(1);
        #pragma unroll
        for (int qs = 0; qs < 2; ++qs)
            #pragma unroll
            for (int s2 = 0; s2 < 4; ++s2) {
                f32x4 a0 = __builtin_amdgcn_mfma_f32_16x16x32_bf16(qf[qs][0], kf[s2][0], zero, 0, 0, 0);
                sv[qs][s2] = __builtin_amdgcn_mfma_f32_16x16x32_bf16(qf[qs][1], kf[s2][1], a0, 0, 0, 0);
            }
        __builtin_amdgcn_s_setprio(0);

        bf16* Pw = &Ps[w][0][0];
        #pragma unroll
        for (int qs = 0; qs < 2; ++qs)
            #pragma unroll
            for (int r = 0; r < 4; ++r) {
                int prow = lg*4 + r;
                #pragma unroll
                for (int s2 = 0; s2 < 4; ++s2) {
                    float pp = __expf(sv[qs][s2][r]);
                    lsum[qs][r] += pp;
                    Pw[qs*(16*72) + prow*72 + s2*16 + lc] = (bf16)pp;
                }
            }
        asm volatile("s_waitcnt lgkmcnt(0)" ::: "memory");
        __builtin_amdgcn_sched_barrier(0);

        bf16x8 pf[2][2];
        #pragma unroll
        for (int qs = 0; qs < 2; ++qs)
            #pragma unroll
            for (int ks = 0; ks < 2; ++ks)
                pf[qs][ks] = *(const bf16x8*)(Pw + qs*(16*72) + lc*72 + (ks*4 + lg)*8);
        bf16x8 vf[4][2];
        #pragma unroll
        for (int dt = 0; dt < 4; ++dt) {
            int row = dt*16 + lc;
            #pragma unroll
            for (int ks = 0; ks < 2; ++ks)
                vf[dt][ks] = *(const bf16x8*)(Vc + row*64 + (((ks*4 + lg) ^ (row & 7)) * 8));
        }
        __builtin_amdgcn_s_setprio(1);
        #pragma unroll
        for (int qs = 0; qs < 2; ++qs)
            #pragma unroll
            for (int dt = 0; dt < 4; ++dt) {
                oacc[qs][dt] = __builtin_amdgcn_mfma_f32_16x16x32_bf16(pf[qs][0], vf[dt][0], oacc[qs][dt], 0, 0, 0);
                oacc[qs][dt] = __builtin_amdgcn_mfma_f32_16x16x32_bf16(pf[qs][1], vf[dt][1], oacc[qs][dt], 0, 0, 0);
            }
        __builtin_amdgcn_s_setprio(0);

        __builtin_amdgcn_s_barrier();
        if (st + 2 < NS) {
            long t2 = (long)(st + 2) * 64;
            gload16(gK + t2*HH, (bf16*)Kc + ldsO);
            gload16(gV + t2,    (bf16*)Vc + ldsO);
        }
    }

    #pragma unroll
    for (int qs = 0; qs < 2; ++qs)
        #pragma unroll
        for (int r = 0; r < 4; ++r) {
            float l = lsum[qs][r];
            l += __shfl_xor(l, 1);
            l += __shfl_xor(l, 2);
            l += __shfl_xor(l, 4);
            l += __shfl_xor(l, 8);
            float inv = 1.0f / l;
            long row = (long)b*SUx + qc*256 + w*32 + qs*16 + lg*4 + r;
            #pragma unroll
            for (int dt = 0; dt < 4; ++dt)
                o[row*HH + h*64 + dt*16 + lc] = (bf16)(oacc[qs][dt][r] * inv);
        }
}

// =============================== launcher ===============================
extern "C" void kernel_launch(void* const* d_in, const int* in_sizes, int n_in,
                              void* d_out, int out_size, void* d_ws, size_t ws_size,
                              hipStream_t stream)
{
    const float* hs  = (const float*)d_in[0];
    const float* Wup = (const float*)d_in[1];
    const float* bup = (const float*)d_in[2];
    const float* anw = (const float*)d_in[3];
    const float* Wq  = (const float*)d_in[4];
    const float* Wk  = (const float*)d_in[5];
    const float* Wv  = (const float*)d_in[6];
    const float* Wo  = (const float*)d_in[7];
    const float* mnw = (const float*)d_in[8];
    const float* Wg  = (const float*)d_in[9];
    const float* Wu  = (const float*)d_in[10];
    const float* Wd  = (const float*)d_in[11];
    float* outp = (float*)d_out;

    char* p = (char*)d_ws;
    auto take = [&](size_t bytes) -> void* {
        void* r = (void*)p;
        p += (bytes + 255) & ~(size_t)255;
        return r;
    };

    bf16* wq  = (bf16*)take((size_t)HH*HH*2);
    bf16* wk  = (bf16*)take(2 * (size_t)HH*HH*2);      // wv contiguous after wk
    bf16* wv  = wk + (size_t)HH*HH;
    bf16* wo  = (bf16*)take((size_t)HH*HH*2);
    bf16* wgu = (bf16*)take(2 * (size_t)INTERx*HH*2);  // [Wg ; Wu] contiguous
    bf16* wd  = (bf16*)take((size_t)INTERx*HH*2);
    bf16* wup = (bf16*)take((size_t)SUx*SS*2);
    bf16* ht  = (bf16*)take((size_t)NB*HH*SS*2);
    bf16* resb= (bf16*)take((size_t)NB*TT*HH*2);
    float* x1f= (float*)take((size_t)NB*SUx*HH*4);
    bf16* x1b = (bf16*)take((size_t)NB*SUx*HH*2);
    float* upf= (float*)take((size_t)NB*SUx*HH*4);   // later reused as x_attn

    size_t attn_bytes = (size_t)NB*SUx*HH*2 + 3*(size_t)NB*TT*HH*2 + (size_t)NB*SUx*HH*2;
    size_t mlp_bytes  = (size_t)NB*SUx*HH*4 + (size_t)NB*SUx*HH*2 + (size_t)NB*SUx*INTERx*2;
    char* un = (char*)take(attn_bytes > mlp_bytes ? attn_bytes : mlp_bytes);
    bf16* qb  = (bf16*)un;
    bf16* kb  = qb  + (size_t)NB*SUx*HH;
    bf16* vb  = kb  + (size_t)NB*TT*HH;
    bf16* vtb = vb  + (size_t)NB*TT*HH;
    bf16* ob  = vtb + (size_t)NB*TT*HH;
    float* x2f= (float*)un;
    bf16* x2b = (bf16*)(un + (size_t)NB*SUx*HH*4);
    bf16* gb  = x2b + (size_t)NB*SUx*HH;

    // ---- 1. single fused cast dispatch ----
    CastArgs ca;
    int blk = 0;
    auto seg = [&](int i, const float* s, bf16* d, long nelem) {
        ca.src[i] = s; ca.dst[i] = d; ca.blk0[i] = blk;
        blk += (int)(nelem / 2048);
    };
    seg(0, Wq,  wq,  (long)HH*HH);
    seg(1, Wk,  wk,  (long)HH*HH);
    seg(2, Wv,  wv,  (long)HH*HH);
    seg(3, Wo,  wo,  (long)HH*HH);
    seg(4, Wg,  wgu, (long)INTERx*HH);
    seg(5, Wu,  wgu + (size_t)INTERx*HH, (long)INTERx*HH);
    seg(6, Wd,  wd,  (long)INTERx*HH);
    seg(7, Wup, wup, (long)SUx*SS);
    seg(8, hs,                 resb,                   (long)SS*HH);
    seg(9, hs + (size_t)SS*HH, resb + (size_t)TT*HH,   (long)SS*HH);
    ca.blk0[10] = blk;
    cast_all_k<<<dim3(blk), 256, 0, stream>>>(ca);

    // ---- 2. h^T (bf16): [b][s][d] -> [b][d][s] ----
    transpose_k<float><<<dim3(SS/64, HH/64, NB), 256, 0, stream>>>(
        hs, ht, HH, SS, 1, (long)SS*HH, 0, (long)HH*SS, 0);

    // ---- 3. upsample: up[b,t,d] = sum_s Wup[t,s] h[b,s,d] + bup[t] ----
    gemm_k<0><<<dim3(HH/128, SUx/128, NB), 512, 0, stream>>>(
        wup, ht, HH, SS, 0, (long)HH*SS,
        resb + (size_t)SS*HH, nullptr, (long)TT*HH,
        upf, (long)SUx*HH,
        nullptr, 0, bup, 1.0f, 0);

    // ---- 4. x1 = rmsnorm(up) ----
    rmsnorm_k<<<dim3(NB*SUx), 256, 0, stream>>>(upf, anw, x1b, x1f);

    // ---- 5. merged Q + K|V projections (1024 blocks, BK=64) ----
    qkv_k<<<dim3(1024), 512, 0, stream>>>(x1b, wq, qb, resb, wk, kb, vb);

    // ---- 6. V^T per head ----
    transpose_k<bf16><<<dim3(TT/64, 1, NB*32), 256, 0, stream>>>(
        vb, vtb, HH, TT, 32, (long)TT*HH, 64, (long)32*64*TT, (long)64*TT);

    // ---- 7. attention ----
    attn_k<<<dim3(SUx/256, 32, NB), 512, 0, stream>>>(qb, kb, vtb, ob);

    // ---- 8. x_attn = o @ Wo^T + x1 ----
    gemm_k<0><<<dim3(HH/128, (NB*SUx)/128, 1), 512, 0, stream>>>(
        ob, wo, HH, HH, 0, 0, nullptr, nullptr, 0, upf, 0, x1f, 0, nullptr, 1.0f, 0);

    // ---- 9. x2 = rmsnorm(x_attn) ----
    rmsnorm_k<<<dim3(NB*SUx), 256, 0, stream>>>(upf, mnw, x2b, x2f);

    // ---- 10. gated MLP, fully fused (BK=64, L2 super-tile decode) ----
    gemm_k<1><<<dim3((2*INTERx)/128, (NB*SUx)/128, 1), 512, 0, stream>>>(
        x2b, wgu, INTERx, HH, 0, 0, gb, nullptr, 0, nullptr, 0, nullptr, 0, nullptr, 1.0f, 0);

    // ---- 11. out = gb @ Wd^T + x2 ----
    gemm_k<0><<<dim3(HH/128, (NB*SUx)/128, 1), 512, 0, stream>>>(
        gb, wd, HH, INTERx, 0, 0, nullptr, nullptr, 0, outp, 0, x2f, 0, nullptr, 1.0f, 0);

    (void)in_sizes; (void)n_in; (void)out_size; (void)ws_size;
}

// Round 17
// 459.097 us; speedup vs baseline: 1.1041x; 1.0132x over previous
//
#include <hip/hip_runtime.h>

typedef __bf16 bf16;
typedef __bf16 bf16x8 __attribute__((ext_vector_type(8)));
typedef float  f32x4  __attribute__((ext_vector_type(4)));
typedef unsigned int u32x4 __attribute__((ext_vector_type(4)));

#define NB 2
#define SS 512
#define HH 2048
#define SUx 1024
#define TT 1536
#define INTERx 5632

// ---------------- async global -> LDS, 16B per lane ----------------
__device__ __forceinline__ void gload16(const void* g, void* l)
{
    __builtin_amdgcn_global_load_lds(
        (const __attribute__((address_space(1))) void*)g,
        (__attribute__((address_space(3))) void*)l, 16, 0, 0);
}

// ---------------- fused cast: all fp32->bf16 segments in ONE dispatch ----------------
struct CastArgs {
    const float* src[10];
    bf16*        dst[10];
    int          blk0[11];   // prefix block starts; blk0[10] = total blocks
};

__global__ __launch_bounds__(256)
void cast_all_k(CastArgs a)
{
    int b = blockIdx.x;
    int s = 0;
    #pragma unroll
    for (int i = 1; i < 10; ++i) if (b >= a.blk0[i]) s = i;
    long idx = ((long)(b - a.blk0[s]) * 256 + threadIdx.x) * 8;
    const float* in = a.src[s];
    bf16* out = a.dst[s];
    f32x4 va = *(const f32x4*)(in + idx);
    f32x4 vb = *(const f32x4*)(in + idx + 4);
    bf16x8 o;
    o[0]=(bf16)va[0]; o[1]=(bf16)va[1]; o[2]=(bf16)va[2]; o[3]=(bf16)va[3];
    o[4]=(bf16)vb[0]; o[5]=(bf16)vb[1]; o[6]=(bf16)vb[2]; o[7]=(bf16)vb[3];
    *(bf16x8*)(out + idx) = o;
}

// ------------- transpose [R][C] -> [C][R] (bf16 out), 64x64 tiles -------------
template <typename TIN>
__global__ __launch_bounds__(256)
void transpose_k(const TIN* __restrict__ in, bf16* __restrict__ out,
                 int inRS, int outRS, int nz2,
                 long inZ1, long inZ2, long outZ1, long outZ2)
{
    __shared__ bf16 tile[64][65];
    int z1 = blockIdx.z / nz2, z2 = blockIdx.z % nz2;
    const TIN* ip = in + (long)z1*inZ1 + (long)z2*inZ2
                  + (long)blockIdx.x*64*inRS + (long)blockIdx.y*64;
    bf16* op = out + (long)z1*outZ1 + (long)z2*outZ2
             + (long)blockIdx.y*64*outRS + (long)blockIdx.x*64;
    int tc = threadIdx.x & 63, tr = threadIdx.x >> 6;
    #pragma unroll
    for (int rr = 0; rr < 64; rr += 4)
        tile[rr+tr][tc] = (bf16)(float)ip[(long)(rr+tr)*inRS + tc];
    __syncthreads();
    #pragma unroll
    for (int cc = 0; cc < 64; cc += 4)
        op[(long)(cc+tr)*outRS + tc] = tile[tc][cc+tr];
}

// ---------------- RMSNorm over H=2048, one block per row ----------------
__global__ __launch_bounds__(256)
void rmsnorm_k(const float* __restrict__ x, const float* __restrict__ w,
               bf16* __restrict__ yb, float* __restrict__ yf)
{
    long row = blockIdx.x;
    const float* xp = x + row * HH;
    int t = threadIdx.x;
    f32x4 v0 = *(const f32x4*)(xp + t*8);
    f32x4 v1 = *(const f32x4*)(xp + t*8 + 4);
    float ss = 0.f;
    #pragma unroll
    for (int j = 0; j < 4; ++j) ss += v0[j]*v0[j] + v1[j]*v1[j];
    #pragma unroll
    for (int off = 32; off > 0; off >>= 1) ss += __shfl_xor(ss, off);
    __shared__ float red[4];
    if ((t & 63) == 0) red[t >> 6] = ss;
    __syncthreads();
    float tot = red[0] + red[1] + red[2] + red[3];
    float inv = rsqrtf(tot * (1.0f/(float)HH) + 1e-6f);
    f32x4 w0 = *(const f32x4*)(w + t*8);
    f32x4 w1 = *(const f32x4*)(w + t*8 + 4);
    f32x4 y0, y1; bf16x8 ob;
    #pragma unroll
    for (int j = 0; j < 4; ++j) {
        y0[j] = v0[j] * inv * w0[j];
        y1[j] = v1[j] * inv * w1[j];
        ob[j]   = (bf16)y0[j];
        ob[4+j] = (bf16)y1[j];
    }
    *(bf16x8*)(yb + row*HH + t*8) = ob;
    if (yf) {
        *(f32x4*)(yf + row*HH + t*8)     = y0;
        *(f32x4*)(yf + row*HH + t*8 + 4) = y1;
    }
}

// ---------------- GEMM body: 128x128 tile, BK=64, 8 waves (2x4), 64x32/wave ----------------
// DEPTH=1: single 32KB buffer, stage -> vmcnt(0) -> barrier -> compute ->
//   barrier (m97 drain pattern). 4 blocks/CU co-resident -> cross-block
//   overlap hides the drain. For big grids (MLP 1408, qkv 1024 blocks).
// DEPTH>=2: multi-buffered counted vmcnt (r9 schedule, generalized): allow
//   (DEPTH-1) tiles in flight, vmcnt(4*ahead). DEPTH=4 (128KB LDS) for
//   1-block/CU grids -> ~3 K-steps of HBM-latency lookahead.
// Both-sides XOR swizzle (conflict-free), XCD-bijective block swizzle,
// GU=1: L2 super-tile decode + interleaved Wg/Wu rows + silu(g)*u epilogue.
template <int GU, int DEPTH>
__device__ __forceinline__
void gemm_body(const bf16* __restrict__ A, const bf16* __restrict__ Bw,
               int Nsplit, int K,
               long sA, long sB,
               bf16* __restrict__ Cb, bf16* __restrict__ Cb2, long sCb,
               float* __restrict__ C32, long sC32,
               const float* __restrict__ res, long sRes,
               const float* __restrict__ bias,
               float scale, int doSilu,
               int lin, int gx, int nwg,
               bf16* Asmem, bf16* Bsmem)
{
    int z = blockIdx.z;
    const bf16* Ap = A + (long)z * sA;

    int n0, m0;
    if (GU) {
        // MLP grid: gx = 88 panels, 16 m-blocks. xcd c owns panels [11c,11c+11).
        // Within XCD: 8-m-row strips swept panel-by-panel (L2 working set fits).
        int c = lin & 7, off = lin >> 3;
        int gx8 = gx >> 3;
        int perStrip = gx8 * 8;
        int a = off / perStrip;
        int r = off - a * perStrip;
        int m = a * 8 + (r & 7);
        int nIdx = c * gx8 + (r >> 3);
        n0 = nIdx * 128; m0 = m * 128;
    } else {
        int qq = nwg >> 3, r8 = nwg & 7;
        int xcd = lin & 7, off = lin >> 3;
        int wg = (xcd < r8 ? xcd * (qq + 1) : r8 * (qq + 1) + (xcd - r8) * qq) + off;
        n0 = (wg % gx) * 128; m0 = (wg / gx) * 128;
    }

    int t = threadIdx.x, lane = t & 63, w = t >> 6;
    int wr = w >> 2, wc = w & 3;            // 2x4 wave grid, 64x32 per wave
    int lc = lane & 15, lg = lane >> 4;

    // staging: instr i, wave w covers LDS rows (i*8+w)*8..+8; lane l ->
    // row += (l>>3), slot l&7; source slot pre-swizzled ^ (row&7).
    int lr = lane >> 3, ls = lane & 7;
    const bf16* gA[2]; const bf16* gB[2];
    int ldsOff[2];
    #pragma unroll
    for (int i = 0; i < 2; ++i) {
        int r = (i*8 + w)*8 + lr;
        gA[i] = Ap + (long)(m0 + r) * K + (ls ^ lr) * 8;
        if (GU) {
            long grow = (long)(n0 >> 1) + (r >> 1);
            gB[i] = Bw + ((r & 1) ? (long)INTERx * K : 0) + grow * K + (ls ^ lr) * 8;
        } else {
            const bf16* Bp = Bw + (long)z * sB;
            gB[i] = Bp + (long)(n0 + r) * K + (ls ^ lr) * 8;
        }
        ldsOff[i] = (i*8 + w) * 512;
    }

    f32x4 zero = {0.f, 0.f, 0.f, 0.f};
    f32x4 acc[4][2];
    #pragma unroll
    for (int i = 0; i < 4; ++i)
        #pragma unroll
        for (int j = 0; j < 2; ++j) acc[i][j] = zero;

    auto stage = [&](int buf, int ti) {
        long ko = (long)ti * 64;
        #pragma unroll
        for (int i = 0; i < 2; ++i) {
            gload16(gA[i] + ko, Asmem + buf*(128*64) + ldsOff[i]);
            gload16(gB[i] + ko, Bsmem + buf*(128*64) + ldsOff[i]);
        }
    };

    auto compute = [&](int buf) {
        const bf16* Asc = Asmem + buf * (128*64);
        const bf16* Bsc = Bsmem + buf * (128*64);
        #pragma unroll
        for (int kk = 0; kk < 2; ++kk) {
            bf16x8 af[4], bfv[2];
            #pragma unroll
            for (int i = 0; i < 4; ++i) {
                int rA = wr*64 + i*16 + lc;
                af[i]  = *(const bf16x8*)(Asc + rA*64 + (((kk*4 + lg) ^ (rA & 7)) * 8));
            }
            #pragma unroll
            for (int j = 0; j < 2; ++j) {
                int rB = wc*32 + j*16 + lc;
                bfv[j] = *(const bf16x8*)(Bsc + rB*64 + (((kk*4 + lg) ^ (rB & 7)) * 8));
            }
            __builtin_amdgcn_s_setprio(1);
            #pragma unroll
            for (int i = 0; i < 4; ++i)
                #pragma unroll
                for (int j = 0; j < 2; ++j)
                    acc[i][j] = __builtin_amdgcn_mfma_f32_16x16x32_bf16(af[i], bfv[j], acc[i][j], 0, 0, 0);
            __builtin_amdgcn_s_setprio(0);
        }
    };

    int NKI = K >> 6;
    if (DEPTH == 1) {
        // single-buffer drain: cross-block overlap (4 blocks/CU) hides stalls
        for (int ks = 0; ks < NKI; ++ks) {
            stage(0, ks);
            asm volatile("s_waitcnt vmcnt(0)" ::: "memory");
            __builtin_amdgcn_s_barrier();
            __builtin_amdgcn_sched_barrier(0);
            compute(0);
            __builtin_amdgcn_s_barrier();
        }
    } else {
        #pragma unroll
        for (int d = 0; d < DEPTH; ++d)
            if (d < NKI) stage(d, d);
        int cur = 0;
        for (int ks = 0; ks < NKI; ++ks) {
            int ahead = NKI - 1 - ks;
            if (ahead > DEPTH - 1) ahead = DEPTH - 1;
            if      (DEPTH > 3 && ahead >= 3) asm volatile("s_waitcnt vmcnt(12)" ::: "memory");
            else if (DEPTH > 2 && ahead == 2) asm volatile("s_waitcnt vmcnt(8)"  ::: "memory");
            else if (ahead == 1)              asm volatile("s_waitcnt vmcnt(4)"  ::: "memory");
            else                              asm volatile("s_waitcnt vmcnt(0)"  ::: "memory");
            __builtin_amdgcn_s_barrier();
            __builtin_amdgcn_sched_barrier(0);
            compute(cur);
            __builtin_amdgcn_s_barrier();
            if (ks + DEPTH < NKI) stage(cur, ks + DEPTH);
            cur = (cur + 1 == DEPTH) ? 0 : cur + 1;
        }
    }

    if (GU) {
        #pragma unroll
        for (int i = 0; i < 4; ++i) {
            #pragma unroll
            for (int j = 0; j < 2; ++j) {
                int tc2 = wc*32 + j*16 + lc;
                int colp = (n0 >> 1) + (tc2 >> 1);
                #pragma unroll
                for (int r = 0; r < 4; ++r) {
                    int row = m0 + wr*64 + i*16 + lg*4 + r;
                    float v = acc[i][j][r];
                    float pv = __shfl_xor(v, 1);
                    float g  = (lc & 1) ? pv : v;
                    float uu = (lc & 1) ? v  : pv;
                    float prod = (g / (1.f + __expf(-g))) * uu;
                    if (!(lc & 1))
                        Cb[(long)row * Nsplit + colp] = (bf16)prod;
                }
            }
        }
    } else {
        #pragma unroll
        for (int i = 0; i < 4; ++i) {
            #pragma unroll
            for (int j = 0; j < 2; ++j) {
                int col = n0 + wc*32 + j*16 + lc;
                bf16* dst = Cb; int c2 = col;
                if (Cb2 && col >= Nsplit) { dst = Cb2; c2 = col - Nsplit; }
                int firstHalf = (col < Nsplit);
                #pragma unroll
                for (int r = 0; r < 4; ++r) {
                    int row = m0 + wr*64 + i*16 + lg*4 + r;
                    float v = acc[i][j][r] * scale;
                    if (bias)   v += bias[row];
                    if (doSilu && firstHalf) v = v / (1.f + __expf(-v));
                    long off = (long)row * Nsplit + c2;
                    if (res)  v += res[(long)z * sRes + off];
                    if (C32)  C32[(long)z * sC32 + off] = v;
                    if (dst)  dst[(long)z * sCb + off] = (bf16)v;
                }
            }
        }
    }
}

// standard wrapper: 2D/3D grid
template <int GU, int DEPTH>
__global__ __launch_bounds__(512)
void gemm_k(const bf16* __restrict__ A, const bf16* __restrict__ Bw,
            int Nsplit, int K,
            long sA, long sB,
            bf16* __restrict__ Cb, bf16* __restrict__ Cb2, long sCb,
            float* __restrict__ C32, long sC32,
            const float* __restrict__ res, long sRes,
            const float* __restrict__ bias,
            float scale, int doSilu)
{
    __shared__ alignas(16) bf16 As[DEPTH][128 * 64];
    __shared__ alignas(16) bf16 Bs[DEPTH][128 * 64];
    int gx = gridDim.x;
    int nwg = gx * gridDim.y;
    int lin = blockIdx.y * gx + blockIdx.x;
    gemm_body<GU, DEPTH>(A, Bw, Nsplit, K, sA, sB, Cb, Cb2, sCb, C32, sC32,
                         res, sRes, bias, scale, doSilu, lin, gx, nwg,
                         &As[0][0], &Bs[0][0]);
}

// merged Q + K|V projections, single-buffer (32KB -> 4 blocks/CU):
// blocks 0..255 -> Q (16x16), 256..1023 -> K|V (32x24)
__global__ __launch_bounds__(512)
void qkv_k(const bf16* __restrict__ x1b, const bf16* __restrict__ wq,
           bf16* __restrict__ qb,
           const bf16* __restrict__ resb, const bf16* __restrict__ wk,
           bf16* __restrict__ kb, bf16* __restrict__ vb)
{
    __shared__ alignas(16) bf16 As[128 * 64];
    __shared__ alignas(16) bf16 Bs[128 * 64];
    int lin = blockIdx.x;
    if (lin < 256) {
        gemm_body<0, 1>(x1b, wq, HH, HH, 0, 0, qb, nullptr, 0, nullptr, 0,
                        nullptr, 0, nullptr, 0.125f, 0, lin, 16, 256,
                        &As[0], &Bs[0]);
    } else {
        gemm_body<0, 1>(resb, wk, HH, HH, 0, 0, kb, vb, 0, nullptr, 0,
                        nullptr, 0, nullptr, 1.0f, 0, lin - 256, 32, 768,
                        &As[0], &Bs[0]);
    }
}

// ---------------- flash attention: 8 waves/block, LDS-shared K/V (r7) ----------------
__global__ __launch_bounds__(512)
void attn_k(const bf16* __restrict__ q, const bf16* __restrict__ k,
            const bf16* __restrict__ vt, bf16* __restrict__ o)
{
    int qc = blockIdx.x, h = blockIdx.y, b = blockIdx.z;
    int t = threadIdx.x, lane = t & 63, w = t >> 6;
    int lc = lane & 15, lg = lane >> 4;
    const bf16* qp = q  + ((long)(b*SUx + qc*256 + w*32)) * HH + h*64;
    const bf16* kp = k  + ((long)b*TT) * HH + h*64;
    const bf16* vp = vt + ((long)(b*32 + h)) * 64 * TT;

    __shared__ alignas(16) bf16 Ks[2][64*64];
    __shared__ alignas(16) bf16 Vs[2][64*64];
    __shared__ alignas(16) bf16 Ps[8][2][16*72];

    bf16x8 qf[2][2];
    #pragma unroll
    for (int s = 0; s < 2; ++s)
        #pragma unroll
        for (int kk = 0; kk < 2; ++kk)
            qf[s][kk] = *(const bf16x8*)(qp + (long)(s*16 + lc)*HH + kk*32 + lg*8);

    int lr = lane >> 3, ls = lane & 7;
    int srow = w*8 + lr;
    int sslot = ls ^ lr;
    const bf16* gK = kp + (long)srow * HH + sslot*8;
    const bf16* gV = vp + (long)srow * TT + sslot*8;
    int ldsO = w * 512;

    f32x4 zero = {0.f, 0.f, 0.f, 0.f};
    f32x4 oacc[2][4];
    float lsum[2][4];
    #pragma unroll
    for (int qs = 0; qs < 2; ++qs) {
        #pragma unroll
        for (int r = 0; r < 4; ++r) lsum[qs][r] = 0.f;
        #pragma unroll
        for (int dt = 0; dt < 4; ++dt) oacc[qs][dt] = zero;
    }

    const int NS = TT / 64;
    gload16(gK,            &Ks[0][0] + ldsO);
    gload16(gV,            &Vs[0][0] + ldsO);
    gload16(gK + 64L*HH,   &Ks[1][0] + ldsO);
    gload16(gV + 64,       &Vs[1][0] + ldsO);

    for (int st = 0; st < NS; ++st) {
        int cur = st & 1;
        const bf16* Kc = &Ks[cur][0];
        const bf16* Vc = &Vs[cur][0];

        if (st == NS - 1) asm volatile("s_waitcnt vmcnt(0)" ::: "memory");
        else              asm volatile("s_waitcnt vmcnt(2)" ::: "memory");
        __builtin_amdgcn_s_barrier();
        __builtin_amdgcn_sched_barrier(0);

        bf16x8 kf[4][2];
        #pragma unroll
        for (int s2 = 0; s2 < 4; ++s2) {
            int row = s2*16 + lc;
            #pragma unroll
            for (int kk = 0; kk < 2; ++kk)
                kf[s2][kk] = *(const bf16x8*)(Kc + row*64 + (((kk*4 + lg) ^ (row & 7)) * 8));
        }
        f32x4 sv[2][4];
        __builtin_amdgcn_s_setprio(1);
        #pragma unroll
        for (int qs = 0; qs < 2; ++qs)
            #pragma unroll
            for (int s2 = 0; s2 < 4; ++s2) {
                f32x4 a0 = __builtin_amdgcn_mfma_f32_16x16x32_bf16(qf[qs][0], kf[s2][0], zero, 0, 0, 0);
                sv[qs][s2] = __builtin_amdgcn_mfma_f32_16x16x32_bf16(qf[qs][1], kf[s2][1], a0, 0, 0, 0);
            }
        __builtin_amdgcn_s_setprio(0);

        bf16* Pw = &Ps[w][0][0];
        #pragma unroll
        for (int qs = 0; qs < 2; ++qs)
            #pragma unroll
            for (int r = 0; r < 4; ++r) {
                int prow = lg*4 + r;
                #pragma unroll
                for (int s2 = 0; s2 < 4; ++s2) {
                    float pp = __expf(sv[qs][s2][r]);
                    lsum[qs][r] += pp;
                    Pw[qs*(16*72) + prow*72 + s2*16 + lc] = (bf16)pp;
                }
            }
        asm volatile("s_waitcnt lgkmcnt(0)" ::: "memory");
        __builtin_amdgcn_sched_barrier(0);

        bf16x8 pf[2][2];
        #pragma unroll
        for (int qs = 0; qs < 2; ++qs)
            #pragma unroll
            for (int ks = 0; ks < 2; ++ks)
                pf[qs][ks] = *(const bf16x8*)(Pw + qs*(16*72) + lc*72 + (ks*4 + lg)*8);
        bf16x8 vf[4][2];
        #pragma unroll
        for (int dt = 0; dt < 4; ++dt) {
            int row = dt*16 + lc;
            #pragma unroll
            for (int ks = 0; ks < 2; ++ks)
                vf[dt][ks] = *(const bf16x8*)(Vc + row*64 + (((ks*4 + lg) ^ (row & 7)) * 8));
        }
        __builtin_amdgcn_s_setprio(1);
        #pragma unroll
        for (int qs = 0; qs < 2; ++qs)
            #pragma unroll
            for (int dt = 0; dt < 4; ++dt) {
                oacc[qs][dt] = __builtin_amdgcn_mfma_f32_16x16x32_bf16(pf[qs][0], vf[dt][0], oacc[qs][dt], 0, 0, 0);
                oacc[qs][dt] = __builtin_amdgcn_mfma_f32_16x16x32_bf16(pf[qs][1], vf[dt][1], oacc[qs][dt], 0, 0, 0);
            }
        __builtin_amdgcn_s_setprio(0);

        __builtin_amdgcn_s_barrier();
        if (st + 2 < NS) {
            long t2 = (long)(st + 2) * 64;
            gload16(gK + t2*HH, (bf16*)Kc + ldsO);
            gload16(gV + t2,    (bf16*)Vc + ldsO);
        }
    }

    #pragma unroll
    for (int qs = 0; qs < 2; ++qs)
        #pragma unroll
        for (int r = 0; r < 4; ++r) {
            float l = lsum[qs][r];
            l += __shfl_xor(l, 1);
            l += __shfl_xor(l, 2);
            l += __shfl_xor(l, 4);
            l += __shfl_xor(l, 8);
            float inv = 1.0f / l;
            long row = (long)b*SUx + qc*256 + w*32 + qs*16 + lg*4 + r;
            #pragma unroll
            for (int dt = 0; dt < 4; ++dt)
                o[row*HH + h*64 + dt*16 + lc] = (bf16)(oacc[qs][dt][r] * inv);
        }
}

// =============================== launcher ===============================
extern "C" void kernel_launch(void* const* d_in, const int* in_sizes, int n_in,
                              void* d_out, int out_size, void* d_ws, size_t ws_size,
                              hipStream_t stream)
{
    const float* hs  = (const float*)d_in[0];
    const float* Wup = (const float*)d_in[1];
    const float* bup = (const float*)d_in[2];
    const float* anw = (const float*)d_in[3];
    const float* Wq  = (const float*)d_in[4];
    const float* Wk  = (const float*)d_in[5];
    const float* Wv  = (const float*)d_in[6];
    const float* Wo  = (const float*)d_in[7];
    const float* mnw = (const float*)d_in[8];
    const float* Wg  = (const float*)d_in[9];
    const float* Wu  = (const float*)d_in[10];
    const float* Wd  = (const float*)d_in[11];
    float* outp = (float*)d_out;

    char* p = (char*)d_ws;
    auto take = [&](size_t bytes) -> void* {
        void* r = (void*)p;
        p += (bytes + 255) & ~(size_t)255;
        return r;
    };

    bf16* wq  = (bf16*)take((size_t)HH*HH*2);
    bf16* wk  = (bf16*)take(2 * (size_t)HH*HH*2);      // wv contiguous after wk
    bf16* wv  = wk + (size_t)HH*HH;
    bf16* wo  = (bf16*)take((size_t)HH*HH*2);
    bf16* wgu = (bf16*)take(2 * (size_t)INTERx*HH*2);  // [Wg ; Wu] contiguous
    bf16* wd  = (bf16*)take((size_t)INTERx*HH*2);
    bf16* wup = (bf16*)take((size_t)SUx*SS*2);
    bf16* ht  = (bf16*)take((size_t)NB*HH*SS*2);
    bf16* resb= (bf16*)take((size_t)NB*TT*HH*2);
    float* x1f= (float*)take((size_t)NB*SUx*HH*4);
    bf16* x1b = (bf16*)take((size_t)NB*SUx*HH*2);
    float* upf= (float*)take((size_t)NB*SUx*HH*4);   // later reused as x_attn

    size_t attn_bytes = (size_t)NB*SUx*HH*2 + 3*(size_t)NB*TT*HH*2 + (size_t)NB*SUx*HH*2;
    size_t mlp_bytes  = (size_t)NB*SUx*HH*4 + (size_t)NB*SUx*HH*2 + (size_t)NB*SUx*INTERx*2;
    char* un = (char*)take(attn_bytes > mlp_bytes ? attn_bytes : mlp_bytes);
    bf16* qb  = (bf16*)un;
    bf16* kb  = qb  + (size_t)NB*SUx*HH;
    bf16* vb  = kb  + (size_t)NB*TT*HH;
    bf16* vtb = vb  + (size_t)NB*TT*HH;
    bf16* ob  = vtb + (size_t)NB*TT*HH;
    float* x2f= (float*)un;
    bf16* x2b = (bf16*)(un + (size_t)NB*SUx*HH*4);
    bf16* gb  = x2b + (size_t)NB*SUx*HH;

    // ---- 1. single fused cast dispatch ----
    CastArgs ca;
    int blk = 0;
    auto seg = [&](int i, const float* s, bf16* d, long nelem) {
        ca.src[i] = s; ca.dst[i] = d; ca.blk0[i] = blk;
        blk += (int)(nelem / 2048);
    };
    seg(0, Wq,  wq,  (long)HH*HH);
    seg(1, Wk,  wk,  (long)HH*HH);
    seg(2, Wv,  wv,  (long)HH*HH);
    seg(3, Wo,  wo,  (long)HH*HH);
    seg(4, Wg,  wgu, (long)INTERx*HH);
    seg(5, Wu,  wgu + (size_t)INTERx*HH, (long)INTERx*HH);
    seg(6, Wd,  wd,  (long)INTERx*HH);
    seg(7, Wup, wup, (long)SUx*SS);
    seg(8, hs,                 resb,                   (long)SS*HH);
    seg(9, hs + (size_t)SS*HH, resb + (size_t)TT*HH,   (long)SS*HH);
    ca.blk0[10] = blk;
    cast_all_k<<<dim3(blk), 256, 0, stream>>>(ca);

    // ---- 2. h^T (bf16): [b][s][d] -> [b][d][s] ----
    transpose_k<float><<<dim3(SS/64, HH/64, NB), 256, 0, stream>>>(
        hs, ht, HH, SS, 1, (long)SS*HH, 0, (long)HH*SS, 0);

    // ---- 3. upsample: up[b,t,d] = sum_s Wup[t,s] h[b,s,d] + bup[t] (DEPTH=4) ----
    gemm_k<0, 4><<<dim3(HH/128, SUx/128, NB), 512, 0, stream>>>(
        wup, ht, HH, SS, 0, (long)HH*SS,
        resb + (size_t)SS*HH, nullptr, (long)TT*HH,
        upf, (long)SUx*HH,
        nullptr, 0, bup, 1.0f, 0);

    // ---- 4. x1 = rmsnorm(up) ----
    rmsnorm_k<<<dim3(NB*SUx), 256, 0, stream>>>(upf, anw, x1b, x1f);

    // ---- 5. merged Q + K|V projections (single-buffer, 4 blocks/CU) ----
    qkv_k<<<dim3(1024), 512, 0, stream>>>(x1b, wq, qb, resb, wk, kb, vb);

    // ---- 6. V^T per head ----
    transpose_k<bf16><<<dim3(TT/64, 1, NB*32), 256, 0, stream>>>(
        vb, vtb, HH, TT, 32, (long)TT*HH, 64, (long)32*64*TT, (long)64*TT);

    // ---- 7. attention ----
    attn_k<<<dim3(SUx/256, 32, NB), 512, 0, stream>>>(qb, kb, vtb, ob);

    // ---- 8. x_attn = o @ Wo^T + x1  (DEPTH=4) ----
    gemm_k<0, 4><<<dim3(HH/128, (NB*SUx)/128, 1), 512, 0, stream>>>(
        ob, wo, HH, HH, 0, 0, nullptr, nullptr, 0, upf, 0, x1f, 0, nullptr, 1.0f, 0);

    // ---- 9. x2 = rmsnorm(x_attn) ----
    rmsnorm_k<<<dim3(NB*SUx), 256, 0, stream>>>(upf, mnw, x2b, x2f);

    // ---- 10. gated MLP, fully fused (single-buffer + L2 super-tile decode) ----
    gemm_k<1, 1><<<dim3((2*INTERx)/128, (NB*SUx)/128, 1), 512, 0, stream>>>(
        x2b, wgu, INTERx, HH, 0, 0, gb, nullptr, 0, nullptr, 0, nullptr, 0, nullptr, 1.0f, 0);

    // ---- 11. out = gb @ Wd^T + x2  (DEPTH=4) ----
    gemm_k<0, 4><<<dim3(HH/128, (NB*SUx)/128, 1), 512, 0, stream>>>(
        gb, wd, HH, INTERx, 0, 0, nullptr, nullptr, 0, outp, 0, x2f, 0, nullptr, 1.0f, 0);

    (void)in_sizes; (void)n_in; (void)out_size; (void)ws_size;
}